// Round 3
// baseline (117.808 us; speedup 1.0000x reference)
//
#include <hip/hip_runtime.h>
#include <math.h>

#define B_SZ   512
#define M_MIX  32
#define D_DIM  1024
#define T_MAX  4096
#define P3M    96            // 3*M
#define KS     8             // split-K chunks
#define ROWS   8             // batch rows per producer block
#define CHUNK  (D_DIM / KS)  // 128
#define NRG    (B_SZ / ROWS) // 64 row-groups
#define CNT_OFF ((size_t)KS * B_SZ * P3M)   // float offset of counters in ws

// ---------------------------------------------------------------------------
// Phase 1 (device fn): split-K partial GEMM for one (rg, ks) pair.
// ws[ks][b][j] = sum_{d in chunk ks} q[b][d] * W[d][j]
// ---------------------------------------------------------------------------
__device__ __forceinline__ void phase1_params(const float* __restrict__ query,
                                              const float* __restrict__ W,
                                              float* __restrict__ ws,
                                              int rg, int ks, int tid)
{
    __shared__ float sQ[ROWS][CHUNK];
    const int r0 = rg * ROWS;
    const int d0 = ks * CHUNK;

    // stage 8 rows x 128 dims of q: 256 threads x one float4 each
    {
        const int r  = tid >> 5;          // 32 float4 per row
        const int dv = tid & 31;
        const float4 v = reinterpret_cast<const float4*>(
            query + (size_t)(r0 + r) * D_DIM + d0)[dv];
        reinterpret_cast<float4*>(&sQ[r][0])[dv] = v;
    }
    __syncthreads();

    if (tid < 2 * P3M) {
        const int j  = tid % P3M;
        const int h  = tid / P3M;         // 0 or 1 -> rows h*4 .. h*4+3
        const int rb = h * 4;
        const float* Wp = W + (size_t)d0 * P3M + j;
        float a0 = 0.f, a1 = 0.f, a2 = 0.f, a3 = 0.f;
        #pragma unroll 8
        for (int d = 0; d < CHUNK; ++d) {
            const float w = Wp[(size_t)d * P3M];
            a0 = fmaf(sQ[rb + 0][d], w, a0);
            a1 = fmaf(sQ[rb + 1][d], w, a1);
            a2 = fmaf(sQ[rb + 2][d], w, a2);
            a3 = fmaf(sQ[rb + 3][d], w, a3);
        }
        float* o = ws + ((size_t)ks * B_SZ + (size_t)(r0 + rb)) * P3M + j;
        o[0 * P3M] = a0; o[1 * P3M] = a1; o[2 * P3M] = a2; o[3 * P3M] = a3;
    }
    __threadfence();       // each thread releases its own partial stores
    __syncthreads();
}

// ---------------------------------------------------------------------------
// Phase 2 (device fn): phi + masked normalize for batch row b.
// Window pruning: terms with exponent < -37 (|phi| < 1e-16*alpha) are skipped
// wave-uniformly; numerically invisible vs the 2.5e-1 threshold.
// ---------------------------------------------------------------------------
template<int NKS>
__device__ __forceinline__ void phase2_phi(const float* __restrict__ ws,
                                           const float* __restrict__ bias,
                                           const float* __restrict__ prev_kappa,
                                           const int* __restrict__ seqlen,
                                           float* __restrict__ out,
                                           int b, int tid)
{
    __shared__ float sA[M_MIX];   // alpha
    __shared__ float sC[M_MIX];   // -beta * log2(e)
    __shared__ float sK[M_MIX];   // kappa
    __shared__ float sR[M_MIX];   // half-width sqrt(37/beta)
    __shared__ float sRange[2];
    __shared__ float sRed[4];

    if (tid < P3M) {
        float p = bias[tid];
        #pragma unroll
        for (int ks = 0; ks < NKS; ++ks)
            p += ws[((size_t)ks * B_SZ + (size_t)b) * P3M + tid];
        if (tid < M_MIX) {
            sA[tid] = __expf(p);
        } else if (tid < 2 * M_MIX) {
            const float be = __expf(p);
            sC[tid - M_MIX] = -be * 1.44269504f;
            sR[tid - M_MIX] = sqrtf(37.0f / be);
        } else {
            const float ka = prev_kappa[(size_t)b * M_MIX + (tid - 2 * M_MIX)] + __expf(p);
            sK[tid - 2 * M_MIX] = ka;
            out[(size_t)B_SZ * T_MAX + (size_t)b * M_MIX + (tid - 2 * M_MIX)] = ka;
        }
    }
    __syncthreads();

    if (tid < 64) {   // parallel window reduce, mixtures duplicated
        const int m = tid & 31;
        float lo = sK[m] - sR[m];
        float hi = sK[m] + sR[m];
        #pragma unroll
        for (int off = 32; off >= 1; off >>= 1) {
            lo = fminf(lo, __shfl_xor(lo, off));
            hi = fmaxf(hi, __shfl_xor(hi, off));
        }
        if (tid == 0) { sRange[0] = lo; sRange[1] = hi; }
    }
    __syncthreads();

    const float gmin = sRange[0], gmax = sRange[1];
    const float tf = (float)tid;
    const int wbase = tid & ~63;

    float acc[16];
    #pragma unroll
    for (int i = 0; i < 16; ++i) acc[i] = 0.f;

    #pragma unroll
    for (int i = 0; i < 16; ++i) {
        const float wlo = (float)(wbase + i * 256);
        if (gmax >= wlo && gmin <= wlo + 63.0f) {   // wave-uniform skip
            const float t = tf + (float)(i * 256);
            #pragma unroll 4
            for (int m = 0; m < M_MIX; ++m) {
                const float d = sK[m] - t;
                acc[i] += sA[m] * exp2f(sC[m] * d * d);
            }
        }
    }

    const int L = seqlen[b];
    float s = 0.f;
    #pragma unroll
    for (int i = 0; i < 16; ++i) {
        const int t = tid + i * 256;
        if (t >= L) acc[i] = 0.f;
        s += acc[i];
    }
    #pragma unroll
    for (int off = 32; off >= 1; off >>= 1) s += __shfl_xor(s, off);
    if ((tid & 63) == 0) sRed[tid >> 6] = s;
    __syncthreads();
    const float invn = 1.0f / (sRed[0] + sRed[1] + sRed[2] + sRed[3] + 1e-8f);

    float* ob = out + (size_t)b * T_MAX;
    #pragma unroll
    for (int i = 0; i < 16; ++i)
        ob[tid + i * 256] = acc[i] * invn;
}

// ---------------------------------------------------------------------------
// Fused kernel: 512 blocks (== 2/CU, all co-resident). Phase 1 produces
// split-K partials; per-row-group device-scope counters gate phase 2.
// ---------------------------------------------------------------------------
__global__ __launch_bounds__(256) void fused_kernel(const float* __restrict__ query,
                                                    const float* __restrict__ prev_kappa,
                                                    const float* __restrict__ W,
                                                    const float* __restrict__ bias,
                                                    const int* __restrict__ seqlen,
                                                    float* __restrict__ out,
                                                    float* __restrict__ ws)
{
    const int p   = blockIdx.x;
    const int tid = threadIdx.x;
    int* cnt = (int*)(ws + CNT_OFF);

    // ---- phase 1: producer (rg = p&63, ks = p>>6) ----
    phase1_params(query, W, ws, p & (NRG - 1), p >> 6, tid);
    if (tid == 0) atomicAdd(&cnt[p & (NRG - 1)], 1);

    // ---- wait for this row's 8 producers ----
    const int b = p;
    if (tid == 0) {
        while (__hip_atomic_load(&cnt[b / ROWS], __ATOMIC_ACQUIRE,
                                 __HIP_MEMORY_SCOPE_AGENT) < KS) {
            __builtin_amdgcn_s_sleep(2);
        }
    }
    __syncthreads();
    __threadfence();   // acquire: discard stale L1 before reading partials

    // ---- phase 2: consumer for row b ----
    phase2_phi<KS>(ws, bias, prev_kappa, seqlen, out, b, tid);
}

// ---------------- fallback (two-kernel) path, in case ws is tiny ----------
__global__ __launch_bounds__(256) void params_only(const float* __restrict__ query,
                                                   const float* __restrict__ W,
                                                   float* __restrict__ ws)
{
    phase1_params(query, W, ws, blockIdx.x & (NRG - 1), blockIdx.x >> 6, threadIdx.x);
}
__global__ __launch_bounds__(256) void phi_only(const float* __restrict__ ws,
                                                const float* __restrict__ bias,
                                                const float* __restrict__ prev_kappa,
                                                const int* __restrict__ seqlen,
                                                float* __restrict__ out)
{
    phase2_phi<KS>(ws, bias, prev_kappa, seqlen, out, blockIdx.x, threadIdx.x);
}

extern "C" void kernel_launch(void* const* d_in, const int* in_sizes, int n_in,
                              void* d_out, int out_size, void* d_ws, size_t ws_size,
                              hipStream_t stream) {
    const float* query = (const float*)d_in[0];
    const float* prevk = (const float*)d_in[1];
    const float* W     = (const float*)d_in[2];
    const float* bias  = (const float*)d_in[3];
    const int*   msl   = (const int*)d_in[4];
    float* out = (float*)d_out;
    float* ws  = (float*)d_ws;

    const size_t need = (CNT_OFF + NRG) * sizeof(float);
    if (ws_size >= need) {
        hipMemsetAsync((char*)d_ws + CNT_OFF * sizeof(float), 0,
                       NRG * sizeof(int), stream);
        fused_kernel<<<B_SZ, 256, 0, stream>>>(query, prevk, W, bias, msl, out, ws);
    } else {
        params_only<<<NRG * KS, 256, 0, stream>>>(query, W, ws);
        phi_only<<<B_SZ, 256, 0, stream>>>(ws, bias, prevk, msl, out);
    }
}

// Round 4
// 16.523 us; speedup vs baseline: 7.1299x; 7.1299x over previous
//
#include <hip/hip_runtime.h>
#include <math.h>

#define B_SZ   512
#define M_MIX  32
#define D_DIM  1024
#define T_MAX  4096
#define P3M    96    // 3 * M_MIX

// ---------------------------------------------------------------------------
// Kernel 1: split-K partial GEMM. ws[ks][b][j] = sum_{d in chunk ks} q[b][d]*W[d][j]
// Grid: (B/ROWS, KS). Block: 256 threads; threads 0..191 compute (j = tid%96,
// row-half = tid/96, 8 rows each). q chunk staged in LDS as float4; inner loop
// reads q via broadcast ds_read_b128 (wave-uniform address -> conflict-free).
// ROWS=16 gives 4x less W L2 traffic than ROWS=4 (12.5 MB total).
// ---------------------------------------------------------------------------
template<int KS, int ROWS>
__global__ __launch_bounds__(256) void params_kernel(const float* __restrict__ query,
                                                     const float* __restrict__ W,
                                                     float* __restrict__ ws)
{
    constexpr int CHUNK = D_DIM / KS;
    constexpr int C4    = CHUNK / 4;
    constexpr int RH    = ROWS / 2;
    __shared__ float4 sQ4[ROWS][C4];

    const int rg  = blockIdx.x;
    const int ks  = blockIdx.y;
    const int tid = threadIdx.x;
    const int d0  = ks * CHUNK;

    // stage q rows (coalesced float4)
    for (int idx = tid; idx < ROWS * C4; idx += 256) {
        const int r = idx / C4, dv = idx % C4;
        sQ4[r][dv] = reinterpret_cast<const float4*>(
            query + (size_t)(rg * ROWS + r) * D_DIM + d0)[dv];
    }
    __syncthreads();

    if (tid < 2 * P3M) {
        const int j  = tid % P3M;
        const int rb = (tid / P3M) * RH;
        const float* Wp = W + (size_t)d0 * P3M + j;
        float acc[RH];
        #pragma unroll
        for (int r = 0; r < RH; ++r) acc[r] = 0.f;

        #pragma unroll 2
        for (int dq = 0; dq < C4; ++dq) {
            float4 qv[RH];
            #pragma unroll
            for (int r = 0; r < RH; ++r) qv[r] = sQ4[rb + r][dq];
            #pragma unroll
            for (int e = 0; e < 4; ++e) {
                const float w = Wp[(size_t)(dq * 4 + e) * P3M];
                #pragma unroll
                for (int r = 0; r < RH; ++r) {
                    const float q = (e == 0) ? qv[r].x : (e == 1) ? qv[r].y
                                  : (e == 2) ? qv[r].z : qv[r].w;
                    acc[r] = fmaf(q, w, acc[r]);
                }
            }
        }
        float* o = ws + ((size_t)ks * B_SZ + (size_t)(rg * ROWS + rb)) * P3M + j;
        #pragma unroll
        for (int r = 0; r < RH; ++r) o[(size_t)r * P3M] = acc[r];
    }
}

// ---------------------------------------------------------------------------
// Kernel 2: per-row phi + masked normalize. One block (256 thr) per batch row.
// Thread handles t = tid + i*256. Wave-uniform window skip prunes the Gaussian
// evaluation to the active region (terms < e^-37 dropped; invisible vs 2.5e-1
// threshold). Alignments stores are non-temporal (streaming, never re-read).
// ---------------------------------------------------------------------------
template<int KS>
__global__ __launch_bounds__(256) void phi_kernel(const float* __restrict__ ws,
                                                  const float* __restrict__ bias,
                                                  const float* __restrict__ prev_kappa,
                                                  const int* __restrict__ seqlen,
                                                  float* __restrict__ out)
{
    __shared__ float sA[M_MIX];   // alpha
    __shared__ float sC[M_MIX];   // -beta * log2(e)
    __shared__ float sK[M_MIX];   // kappa
    __shared__ float sR[M_MIX];   // window half-width sqrt(37/beta)
    __shared__ float sRange[2];   // gmin, gmax over mixtures
    __shared__ float sRed[4];     // per-wave partial sums

    const int b   = blockIdx.x;
    const int tid = threadIdx.x;

    if (tid < P3M) {
        float p = bias[tid];
        #pragma unroll
        for (int ks = 0; ks < KS; ++ks)
            p += ws[((size_t)ks * B_SZ + (size_t)b) * P3M + tid];
        if (tid < M_MIX) {
            sA[tid] = __expf(p);
        } else if (tid < 2 * M_MIX) {
            const float be = __expf(p);
            sC[tid - M_MIX] = -be * 1.44269504f;
            sR[tid - M_MIX] = 6.0827625f * __frsqrt_rn(be);   // sqrt(37/beta)
        } else {
            const float ka = prev_kappa[(size_t)b * M_MIX + (tid - 2 * M_MIX)] + __expf(p);
            sK[tid - 2 * M_MIX] = ka;
            out[(size_t)B_SZ * T_MAX + (size_t)b * M_MIX + (tid - 2 * M_MIX)] = ka;
        }
    }
    __syncthreads();

    // parallel window reduce: 64 lanes, mixtures duplicated (m = tid&31)
    if (tid < 64) {
        const int m = tid & 31;
        float lo = sK[m] - sR[m];
        float hi = sK[m] + sR[m];
        #pragma unroll
        for (int off = 32; off >= 1; off >>= 1) {
            lo = fminf(lo, __shfl_xor(lo, off));
            hi = fmaxf(hi, __shfl_xor(hi, off));
        }
        if (tid == 0) { sRange[0] = lo; sRange[1] = hi; }
    }
    __syncthreads();

    const float gmin = sRange[0], gmax = sRange[1];
    const float tf = (float)tid;
    const int wbase = tid & ~63;   // wave's first tid

    float acc[16];
    #pragma unroll
    for (int i = 0; i < 16; ++i) acc[i] = 0.f;

    #pragma unroll
    for (int i = 0; i < 16; ++i) {
        const float wlo = (float)(wbase + i * 256);
        if (gmax >= wlo && gmin <= wlo + 63.0f) {   // wave-uniform skip
            const float t = tf + (float)(i * 256);
            #pragma unroll 4
            for (int m = 0; m < M_MIX; ++m) {
                const float d = sK[m] - t;
                acc[i] += sA[m] * exp2f(sC[m] * d * d);
            }
        }
    }

    // mask + per-thread sum
    const int L = seqlen[b];
    float s = 0.f;
    #pragma unroll
    for (int i = 0; i < 16; ++i) {
        const int t = tid + i * 256;
        if (t >= L) acc[i] = 0.f;
        s += acc[i];
    }
    #pragma unroll
    for (int off = 32; off >= 1; off >>= 1) s += __shfl_xor(s, off);
    if ((tid & 63) == 0) sRed[tid >> 6] = s;
    __syncthreads();
    const float invn = 1.0f / (sRed[0] + sRed[1] + sRed[2] + sRed[3] + 1e-8f);

    float* ob = out + (size_t)b * T_MAX;
    #pragma unroll
    for (int i = 0; i < 16; ++i)
        __builtin_nontemporal_store(acc[i] * invn, ob + tid + i * 256);
}

extern "C" void kernel_launch(void* const* d_in, const int* in_sizes, int n_in,
                              void* d_out, int out_size, void* d_ws, size_t ws_size,
                              hipStream_t stream) {
    const float* query = (const float*)d_in[0];
    const float* prevk = (const float*)d_in[1];
    const float* W     = (const float*)d_in[2];
    const float* bias  = (const float*)d_in[3];
    const int*   msl   = (const int*)d_in[4];
    float* out = (float*)d_out;
    float* ws  = (float*)d_ws;

    const size_t per_ks = (size_t)B_SZ * P3M * sizeof(float);
    if (ws_size >= 16 * per_ks) {
        params_kernel<16, 16><<<dim3(B_SZ / 16, 16), 256, 0, stream>>>(query, W, ws);
        phi_kernel<16><<<B_SZ, 256, 0, stream>>>(ws, bias, prevk, msl, out);
    } else if (ws_size >= 4 * per_ks) {
        params_kernel<4, 8><<<dim3(B_SZ / 8, 4), 256, 0, stream>>>(query, W, ws);
        phi_kernel<4><<<B_SZ, 256, 0, stream>>>(ws, bias, prevk, msl, out);
    } else {
        params_kernel<1, 4><<<dim3(B_SZ / 4, 1), 256, 0, stream>>>(query, W, ws);
        phi_kernel<1><<<B_SZ, 256, 0, stream>>>(ws, bias, prevk, msl, out);
    }
}